// Round 1
// baseline (390.900 us; speedup 1.0000x reference)
//
#include <hip/hip_runtime.h>
#include <stdint.h>

typedef __attribute__((ext_vector_type(4))) float f32x4;
typedef __attribute__((ext_vector_type(8))) short bf16x8;
typedef __attribute__((ext_vector_type(4))) unsigned short u16x4;
typedef unsigned short u16;

#define B_ 4
#define S_ 2048
#define D_ 1024
#define H_ 16
#define DK_ 64
#define BS_ (B_*S_)       /* 8192 */
#define NQKV_ (3*H_*DK_)  /* 3072 */

__device__ __forceinline__ u16 f2bf(float x) {
  union { float f; uint32_t u; } c; c.f = x;
  uint32_t r = (c.u + 0x7FFFu + ((c.u >> 16) & 1u)) >> 16;
  return (u16)r;
}

__global__ __launch_bounds__(256) void conv_f32_to_bf16(
    const float* __restrict__ src, u16* __restrict__ dst, int n) {
  int i = (blockIdx.x * 256 + threadIdx.x) * 4;
  if (i >= n) return;
  const float* p = src + i;
  u16x4 o = { f2bf(p[0]), f2bf(p[1]), f2bf(p[2]), f2bf(p[3]) };
  *(u16x4*)(dst + i) = o;
}

// Pack Wq|Wk|Wv ([H,D,64] each) into Wcat[D][3*H*64] bf16, col = (w*16+h)*64+dk
__global__ __launch_bounds__(256) void build_wcat(
    const float* __restrict__ Wq, const float* __restrict__ Wk,
    const float* __restrict__ Wv, u16* __restrict__ dst) {
  long idx = (long)blockIdx.x * 256 + threadIdx.x;   // < 3*16*1024*64
  const int per = H_ * D_ * DK_;
  int w = (int)(idx / per);
  int rem = (int)(idx % per);
  int h = rem / (D_ * DK_);
  int r2 = rem % (D_ * DK_);
  int d = r2 / DK_;
  int dk = r2 % DK_;
  const float* src = (w == 0) ? Wq : ((w == 1) ? Wk : Wv);
  dst[(long)d * NQKV_ + (w * H_ + h) * DK_ + dk] = f2bf(src[rem]);
}

// Generic bf16 MFMA GEMM: C[M,N] = A[M,K] * B[K,N]; 128x128 tile, BK=32.
// OUT_BF16: C is bf16. else: C fp32 with residual add.
template<bool OUT_BF16>
__global__ __launch_bounds__(256) void gemm_bf16(
    const u16* __restrict__ A, const u16* __restrict__ Bm,
    void* __restrict__ Cout, const float* __restrict__ resid,
    int M, int N, int K) {
  __shared__ __attribute__((aligned(16))) u16 Al[128][40];
  __shared__ __attribute__((aligned(16))) u16 Bt[128][40];
  const int tid = threadIdx.x;
  const int wid = tid >> 6;
  const int lane = tid & 63;
  const int wm = (wid >> 1) * 64;
  const int wn = (wid & 1) * 64;
  const int row0 = blockIdx.x * 128;
  const int col0 = blockIdx.y * 128;
  const int fr = lane & 15;
  const int fk = (lane >> 4) * 8;

  const int ar = tid >> 1;            // A stage: row 0..127
  const int ac = (tid & 1) * 16;      // col 0 or 16
  const int bn = tid & 127;           // B stage: col of B
  const int bkg = (tid >> 7) * 16;    // k group 0 or 16

  f32x4 acc[4][4] = {};

  for (int kk = 0; kk < K; kk += 32) {
    const u16* ag = A + (long)(row0 + ar) * K + kk + ac;
    bf16x8 a0 = *(const bf16x8*)ag;
    bf16x8 a1 = *(const bf16x8*)(ag + 8);
    __attribute__((aligned(16))) u16 br[16];
    const u16* bg = Bm + (long)(kk + bkg) * N + col0 + bn;
#pragma unroll
    for (int j = 0; j < 16; ++j) br[j] = bg[(long)j * N];
    __syncthreads();
    *(bf16x8*)&Al[ar][ac] = a0;
    *(bf16x8*)&Al[ar][ac + 8] = a1;
    *(bf16x8*)&Bt[bn][bkg] = *(const bf16x8*)&br[0];
    *(bf16x8*)&Bt[bn][bkg + 8] = *(const bf16x8*)&br[8];
    __syncthreads();
    bf16x8 af[4], bfr[4];
#pragma unroll
    for (int mf = 0; mf < 4; ++mf)
      af[mf] = *(const bf16x8*)&Al[wm + mf * 16 + fr][fk];
#pragma unroll
    for (int nf = 0; nf < 4; ++nf)
      bfr[nf] = *(const bf16x8*)&Bt[wn + nf * 16 + fr][fk];
#pragma unroll
    for (int mf = 0; mf < 4; ++mf)
#pragma unroll
      for (int nf = 0; nf < 4; ++nf)
        acc[mf][nf] = __builtin_amdgcn_mfma_f32_16x16x32_bf16(
            af[mf], bfr[nf], acc[mf][nf], 0, 0, 0);
  }

  const int r0 = (lane >> 4) * 4;
#pragma unroll
  for (int mf = 0; mf < 4; ++mf)
#pragma unroll
    for (int nf = 0; nf < 4; ++nf)
#pragma unroll
      for (int r = 0; r < 4; ++r) {
        long row = row0 + wm + mf * 16 + r0 + r;
        long col = col0 + wn + nf * 16 + fr;
        if constexpr (OUT_BF16) {
          ((u16*)Cout)[row * N + col] = f2bf(acc[mf][nf][r]);
        } else {
          float v = acc[mf][nf][r] + resid[row * N + col];
          ((float*)Cout)[row * N + col] = v;
        }
      }
}

// Flash attention with swapped roles: O[j] = softmax_i(k_j . q_i / 8) v_i
// qkv: [8192][3072] bf16 (cols: h*64 for q, (16+h)*64 for k, (32+h)*64 for v)
// multi: [8192][1024] bf16 out
__global__ __launch_bounds__(256) void attn_kernel(
    const u16* __restrict__ qkv, u16* __restrict__ multi) {
  __shared__ __attribute__((aligned(16))) u16 Kp[64][72];
  __shared__ __attribute__((aligned(16))) u16 Ql[64][72];
  __shared__ __attribute__((aligned(16))) u16 Vt[64][72];
  __shared__ __attribute__((aligned(16))) u16 Pl[64][72];
  const int tid = threadIdx.x;
  const int wid = tid >> 6;
  const int lane = tid & 63;
  const int fr = lane & 15;
  const int fkb = (lane >> 4) * 8;
  const int r0 = (lane >> 4) * 4;

  const int jt = blockIdx.x;           // 0..31
  const int b = blockIdx.y >> 4;
  const int h = blockIdx.y & 15;
  const int cbQ = h * 64;
  const int cbK = (H_ + h) * 64;
  const int cbV = (2 * H_ + h) * 64;
  const long rowb = (long)b * S_;
  const long rj = rowb + jt * 64;

  {  // stage this block's K-proj rows (the "queries" of swapped attention)
    const int r = tid >> 2, q = (tid & 3) * 16;
    const u16* g = qkv + (rj + r) * NQKV_ + cbK + q;
    bf16x8 v0 = *(const bf16x8*)g;
    bf16x8 v1 = *(const bf16x8*)(g + 8);
    *(bf16x8*)&Kp[r][q] = v0;
    *(bf16x8*)&Kp[r][q + 8] = v1;
  }
  __syncthreads();

  f32x4 acc_o[4] = {};
  float m_run[4] = {-1e30f, -1e30f, -1e30f, -1e30f};
  float l_run[4] = {};

  for (int it = 0; it < S_ / 64; ++it) {
    const long ri = rowb + (long)it * 64;
    // global loads to regs (overlap with prior iter's compute)
    const int qr = tid >> 2, qq = (tid & 3) * 16;
    const u16* qg = qkv + (ri + qr) * NQKV_ + cbQ + qq;
    bf16x8 q0 = *(const bf16x8*)qg;
    bf16x8 q1 = *(const bf16x8*)(qg + 8);
    const int vd = tid & 63, vg = (tid >> 6) * 16;
    __attribute__((aligned(16))) u16 vr[16];
    const u16* vgp = qkv + (ri + vg) * NQKV_ + cbV + vd;
#pragma unroll
    for (int j = 0; j < 16; ++j) vr[j] = vgp[(long)j * NQKV_];
    __syncthreads();
    *(bf16x8*)&Ql[qr][qq] = q0;
    *(bf16x8*)&Ql[qr][qq + 8] = q1;
    *(bf16x8*)&Vt[vd][vg] = *(const bf16x8*)&vr[0];
    *(bf16x8*)&Vt[vd][vg + 8] = *(const bf16x8*)&vr[8];
    __syncthreads();

    // S = Kp x Ql^T : wave's 16 j-rows x all 64 i-cols
    f32x4 sa[4] = {};
#pragma unroll
    for (int kc = 0; kc < 2; ++kc) {
      bf16x8 afr = *(const bf16x8*)&Kp[wid * 16 + fr][kc * 32 + fkb];
#pragma unroll
      for (int nf = 0; nf < 4; ++nf) {
        bf16x8 bfr = *(const bf16x8*)&Ql[nf * 16 + fr][kc * 32 + fkb];
        sa[nf] = __builtin_amdgcn_mfma_f32_16x16x32_bf16(afr, bfr, sa[nf], 0, 0, 0);
      }
    }
    // online softmax over i; lane owns rows r0..r0+3 (C-layout), 16 lanes/row
    float rmax[4], fsc[4], rsum[4];
#pragma unroll
    for (int r = 0; r < 4; ++r) {
      float m0 = fmaxf(fmaxf(sa[0][r], sa[1][r]), fmaxf(sa[2][r], sa[3][r]));
#pragma unroll
      for (int msk = 1; msk < 16; msk <<= 1) m0 = fmaxf(m0, __shfl_xor(m0, msk));
      rmax[r] = m0 * 0.125f;
      float mn = fmaxf(m_run[r], rmax[r]);
      fsc[r] = __expf(m_run[r] - mn);
      m_run[r] = mn;
      rsum[r] = 0.f;
    }
    float p[4][4];
#pragma unroll
    for (int nf = 0; nf < 4; ++nf)
#pragma unroll
      for (int r = 0; r < 4; ++r) {
        float pv = __expf(sa[nf][r] * 0.125f - m_run[r]);
        p[nf][r] = pv;
        rsum[r] += pv;
      }
#pragma unroll
    for (int r = 0; r < 4; ++r) {
      float s = rsum[r];
#pragma unroll
      for (int msk = 1; msk < 16; msk <<= 1) s += __shfl_xor(s, msk);
      l_run[r] = l_run[r] * fsc[r] + s;
    }
#pragma unroll
    for (int nf = 0; nf < 4; ++nf)
#pragma unroll
      for (int r = 0; r < 4; ++r) acc_o[nf][r] *= fsc[r];
    // P -> LDS (bf16, A-layout readable)
#pragma unroll
    for (int nf = 0; nf < 4; ++nf)
#pragma unroll
      for (int r = 0; r < 4; ++r)
        Pl[wid * 16 + r0 + r][nf * 16 + fr] = f2bf(p[nf][r]);
    __syncthreads();
    // O += P x V
#pragma unroll
    for (int kc = 0; kc < 2; ++kc) {
      bf16x8 pa = *(const bf16x8*)&Pl[wid * 16 + fr][kc * 32 + fkb];
#pragma unroll
      for (int nf = 0; nf < 4; ++nf) {
        bf16x8 vb = *(const bf16x8*)&Vt[nf * 16 + fr][kc * 32 + fkb];
        acc_o[nf] = __builtin_amdgcn_mfma_f32_16x16x32_bf16(pa, vb, acc_o[nf], 0, 0, 0);
      }
    }
  }
#pragma unroll
  for (int nf = 0; nf < 4; ++nf)
#pragma unroll
    for (int r = 0; r < 4; ++r) {
      long row = rj + wid * 16 + r0 + r;
      int col = h * 64 + nf * 16 + fr;
      multi[row * (H_ * DK_) + col] = f2bf(acc_o[nf][r] / l_run[r]);
    }
}

// In-place LayerNorm over rows of 1024 fp32
__global__ __launch_bounds__(256) void ln_kernel(
    float* __restrict__ out, const float* __restrict__ gamma,
    const float* __restrict__ beta) {
  const int tid = threadIdx.x;
  const int wid = tid >> 6;
  const int lane = tid & 63;
  float* p = out + (long)blockIdx.x * D_;
  const float* pv = p + tid * 4;
  float x0 = pv[0], x1 = pv[1], x2 = pv[2], x3 = pv[3];
  float s = x0 + x1 + x2 + x3;
  float q = x0 * x0 + x1 * x1 + x2 * x2 + x3 * x3;
#pragma unroll
  for (int off = 32; off > 0; off >>= 1) {
    s += __shfl_down(s, off);
    q += __shfl_down(q, off);
  }
  __shared__ float sh[8];
  if (lane == 0) { sh[wid] = s; sh[4 + wid] = q; }
  __syncthreads();
  s = sh[0] + sh[1] + sh[2] + sh[3];
  q = sh[4] + sh[5] + sh[6] + sh[7];
  float mean = s * (1.0f / D_);
  float var = q * (1.0f / D_) - mean * mean;
  float rstd = rsqrtf(var + 1e-5f);
  const float* g = gamma + tid * 4;
  const float* be = beta + tid * 4;
  float* po = p + tid * 4;
  po[0] = (x0 - mean) * rstd * g[0] + be[0];
  po[1] = (x1 - mean) * rstd * g[1] + be[1];
  po[2] = (x2 - mean) * rstd * g[2] + be[2];
  po[3] = (x3 - mean) * rstd * g[3] + be[3];
}

extern "C" void kernel_launch(void* const* d_in, const int* in_sizes, int n_in,
                              void* d_out, int out_size, void* d_ws, size_t ws_size,
                              hipStream_t stream) {
  const float* tokens = (const float*)d_in[0];
  const float* Wq = (const float*)d_in[1];
  const float* Wk = (const float*)d_in[2];
  const float* Wv = (const float*)d_in[3];
  const float* Wo = (const float*)d_in[4];
  const float* gamma = (const float*)d_in[5];
  const float* beta = (const float*)d_in[6];
  float* out = (float*)d_out;

  char* ws = (char*)d_ws;
  u16* tok_bf = (u16*)(ws);                    // 16 MB: tokens bf16 [8192][1024]
  u16* wcat   = (u16*)(ws + 16777216);         // 6 MB : Wcat [1024][3072]
  u16* wo_bf  = (u16*)(ws + 23068672);         // 2 MB : Wo bf16 [1024][1024]
  u16* qkv    = (u16*)(ws + 25165824);         // 48 MB: qkv [8192][3072]
  u16* multi  = (u16*)(ws + 75497472);         // 16 MB: multi [8192][1024]

  conv_f32_to_bf16<<<8192, 256, 0, stream>>>(tokens, tok_bf, BS_ * D_);
  conv_f32_to_bf16<<<1024, 256, 0, stream>>>(Wo, wo_bf, D_ * D_);
  build_wcat<<<12288, 256, 0, stream>>>(Wq, Wk, Wv, wcat);

  // QKV projection: [8192,1024] x [1024,3072] -> bf16 qkv
  gemm_bf16<true><<<dim3(BS_ / 128, NQKV_ / 128), 256, 0, stream>>>(
      tok_bf, wcat, qkv, nullptr, BS_, NQKV_, D_);

  // attention (swapped flash): -> multi [8192][1024] bf16
  attn_kernel<<<dim3(S_ / 64, B_ * H_), 256, 0, stream>>>(qkv, multi);

  // out-proj + residual: [8192,1024] x [1024,1024] + tokens -> fp32 d_out
  gemm_bf16<false><<<dim3(BS_ / 128, D_ / 128), 256, 0, stream>>>(
      multi, wo_bf, out, tokens, BS_, D_, D_);

  // in-place LayerNorm
  ln_kernel<<<BS_, 256, 0, stream>>>(out, gamma, beta);
}